// Round 5
// baseline (1252.137 us; speedup 1.0000x reference)
//
#include <hip/hip_runtime.h>
#include <cstdint>
#include <cstddef>

typedef unsigned short u16;
typedef __attribute__((ext_vector_type(8))) short s8v;   // 8 bf16 in 4 VGPRs
typedef __attribute__((ext_vector_type(4))) float f4v;   // MFMA accumulator

#define D_MODEL 1024
#define D_INNER 2048
#define BT      8192   // B*T
#define TLEN    2048
#define NBATCH  4
#define BSLOT   256    // block-of-8 slots per batch (power of 2)
#define NBLK    255    // blocks per batch: t = 8q+1 .. 8q+8, q in [0,255)

struct alignas(8) U16x4 { u16 x, y, z, w; };

__device__ __forceinline__ u16 f2bf(float f) {
  union { float f; unsigned u; } c; c.f = f;
  unsigned r = c.u + 0x7FFFu + ((c.u >> 16) & 1u);   // RNE
  return (u16)(r >> 16);
}
// bf16 unpack from packed pair (u32): low ch / high ch
__device__ __forceinline__ float blo(unsigned u) {
  union { unsigned u; float f; } c; c.u = u << 16; return c.f;
}
__device__ __forceinline__ float bhi(unsigned u) {
  union { unsigned u; float f; } c; c.u = u & 0xffff0000u; return c.f;
}
// pack two fp32 -> packed bf16 pair (round half up), lo in low 16
__device__ __forceinline__ unsigned pkbf(float lo, float hi) {
  union { float f; unsigned u; } a, b; a.f = lo; b.f = hi;
#if __has_builtin(__builtin_amdgcn_perm)
  return __builtin_amdgcn_perm(b.u + 0x8000u, a.u + 0x8000u, 0x07060302u);
#else
  return ((b.u + 0x8000u) & 0xffff0000u) | ((a.u + 0x8000u) >> 16);
#endif
}

// DPP wave-64 sum: VALU-pipe latency instead of ds_bpermute. Result in lane 63.
#define DPPADD(x, ctrl) \
  ((x) + __builtin_bit_cast(float, __builtin_amdgcn_update_dpp( \
       0, __builtin_bit_cast(int, (x)), (ctrl), 0xF, 0xF, true)))
__device__ __forceinline__ float wave_sum_dpp(float x) {
  x = DPPADD(x, 0x111);  // row_shr:1
  x = DPPADD(x, 0x112);  // row_shr:2
  x = DPPADD(x, 0x114);  // row_shr:4
  x = DPPADD(x, 0x118);  // row_shr:8
  x = DPPADD(x, 0x142);  // row_bcast:15
  x = DPPADD(x, 0x143);  // row_bcast:31
  return x;              // lane 63 = wave sum
}

// async global->LDS, 16B per lane; LDS dest must be wave-uniform base (+lane*16 by HW)
__device__ __forceinline__ void glds16(const u16* g, const u16* lds) {
  __builtin_amdgcn_global_load_lds(
      (const __attribute__((address_space(1))) unsigned int*)(uintptr_t)g,
      (__attribute__((address_space(3))) unsigned int*)(unsigned int)(uintptr_t)lds,
      16, 0, 0);
}

// ---------------------------------------------------------------------------
// GEMM. EPI 0: split N=4096 -> Cb=xi bf16 | Cb2=silu(z) bf16
//       EPI 4: n<2048 -> Cb2 = bf16(1-lam) = bf16(-expm1(sfac*sigmoid(acc+bias)))
//              n>=2048 -> Cb = bf16(acc + bias2)   (v bf16)
//       EPI 3: Cf = acc (final out, fp32)
// ---------------------------------------------------------------------------
template<int EPI>
__global__ __launch_bounds__(256, 2)
void gemm_nt(const u16* __restrict__ A, const u16* __restrict__ B,
             int M, int N, int K,
             float* __restrict__ Cf, u16* __restrict__ Cb, u16* __restrict__ Cb2,
             const float* __restrict__ bias, const float* __restrict__ sfac,
             const float* __restrict__ bias2)
{
  __shared__ u16 lA[128 * 32];
  __shared__ u16 lB[128 * 32];
  const int tid  = threadIdx.x;
  const int wave = tid >> 6, lane = tid & 63;
  const int wm = wave >> 1, wn = wave & 1;
  const int bm0 = blockIdx.y * 128, bn0 = blockIdx.x * 128;

  const int srow = lane >> 2;
  const int scol = (lane & 3) * 8;
  const u16* pa0 = A + (size_t)(bm0 + wave * 32 + srow) * K + scol;
  const u16* pa1 = pa0 + (size_t)16 * K;
  const u16* pb0 = B + (size_t)(bn0 + wave * 32 + srow) * K + scol;
  const u16* pb1 = pb0 + (size_t)16 * K;
  u16* la0 = lA + (wave * 32) * 32;
  u16* la1 = la0 + 16 * 32;
  u16* lb0 = lB + (wave * 32) * 32;
  u16* lb1 = lb0 + 16 * 32;

  const int fr = lane & 15, kq = lane >> 4;
  const u16* fA = lA + (wm * 64 + fr) * 32 + kq * 8;
  const u16* fB = lB + (wn * 64 + fr) * 32 + kq * 8;

  f4v acc[4][4];
  const f4v zf = {0.f, 0.f, 0.f, 0.f};
  for (int i = 0; i < 4; ++i)
    for (int j = 0; j < 4; ++j)
      acc[i][j] = zf;

  for (int k0 = 0; k0 < K; k0 += 32) {
    glds16(pa0 + k0, la0);
    glds16(pa1 + k0, la1);
    glds16(pb0 + k0, lb0);
    glds16(pb1 + k0, lb1);
    __syncthreads();
    s8v af[4], bfv[4];
#pragma unroll
    for (int i = 0; i < 4; ++i) af[i] = *(const s8v*)(fA + i * 16 * 32);
#pragma unroll
    for (int j = 0; j < 4; ++j) bfv[j] = *(const s8v*)(fB + j * 16 * 32);
#pragma unroll
    for (int i = 0; i < 4; ++i)
#pragma unroll
      for (int j = 0; j < 4; ++j)
        acc[i][j] = __builtin_amdgcn_mfma_f32_16x16x32_bf16(af[i], bfv[j], acc[i][j], 0, 0, 0);
    __syncthreads();
  }

  // C/D layout: col = lane&15, row = (lane>>4)*4 + reg
#pragma unroll
  for (int i = 0; i < 4; ++i) {
#pragma unroll
    for (int j = 0; j < 4; ++j) {
#pragma unroll
      for (int r = 0; r < 4; ++r) {
        const int gm = bm0 + wm * 64 + i * 16 + kq * 4 + r;
        const int gn = bn0 + wn * 64 + j * 16 + fr;
        const float val = acc[i][j][r];
        if (EPI == 0) {
          if (gn < D_INNER) {
            Cb[(size_t)gm * D_INNER + gn] = f2bf(val);
          } else {
            const float s = val / (1.f + __expf(-val));  // silu(z)
            Cb2[(size_t)gm * D_INNER + (gn - D_INNER)] = f2bf(s);
          }
        } else if (EPI == 4) {
          if (gn < D_INNER) {
            const float pre = val + bias[gn];
            const float sig = 1.f / (1.f + __expf(-pre));
            const float m = -expm1f(sfac[gn] * sig);   // 1 - lam, full precision
            Cb2[(size_t)gm * D_INNER + gn] = f2bf(m);
          } else {
            Cb[(size_t)gm * D_INNER + (gn - D_INNER)] = f2bf(val + bias2[gn - D_INNER]);
          }
        } else {
          Cf[(size_t)gm * N + gn] = val;
        }
      }
    }
  }
}

__global__ void conv_bf16_kernel(const float* __restrict__ in, u16* __restrict__ out, int n4)
{
  const int i = blockIdx.x * blockDim.x + threadIdx.x;
  if (i >= n4) return;
  const float4 x = ((const float4*)in)[i];
  U16x4 o; o.x = f2bf(x.x); o.y = f2bf(x.y); o.z = f2bf(x.z); o.w = f2bf(x.w);
  ((U16x4*)out)[i] = o;
}

__global__ void sfac_kernel(const float* __restrict__ omega, float* __restrict__ sfac)
{
  const int i = blockIdx.x * blockDim.x + threadIdx.x;
  if (i < D_INNER) sfac[i] = -8.f * log1pf(expf(omega[i]));  // -C*softplus(omega)
}

// v <- v * sqrt(2/(v.v)) per row; 1 wave per row, 4 rows per block.
__global__ __launch_bounds__(256)
void vscale_kernel(u16* __restrict__ v)
{
  const int row  = blockIdx.x * 4 + (threadIdx.x >> 6);
  const int lane = threadIdx.x & 63;
  uint4* p = (uint4*)(v + (size_t)row * D_INNER + lane * 32);  // 32 ch/lane
  uint4 a[4];
#pragma unroll
  for (int i = 0; i < 4; ++i) a[i] = p[i];
  float s = 0.f;
#pragma unroll
  for (int i = 0; i < 4; ++i) {
    const unsigned w[4] = {a[i].x, a[i].y, a[i].z, a[i].w};
#pragma unroll
    for (int j = 0; j < 4; ++j) {
      const float f0 = blo(w[j]), f1 = bhi(w[j]);
      s += f0 * f0 + f1 * f1;
    }
  }
  s += __shfl_down(s, 32); s += __shfl_down(s, 16); s += __shfl_down(s, 8);
  s += __shfl_down(s, 4);  s += __shfl_down(s, 2);  s += __shfl_down(s, 1);
  const float sc = sqrtf(2.f / __shfl(s, 0));
#pragma unroll
  for (int i = 0; i < 4; ++i) {
    const unsigned w[4] = {a[i].x, a[i].y, a[i].z, a[i].w};
    unsigned o[4];
#pragma unroll
    for (int j = 0; j < 4; ++j) o[j] = pkbf(blo(w[j]) * sc, bhi(w[j]) * sc);
    uint4 ov; ov.x = o[0]; ov.y = o[1]; ov.z = o[2]; ov.w = o[3];
    p[i] = ov;
  }
}

// ---------------------------------------------------------------------------
// Block precompute (G=8 WY-style). Block q of batch b covers t = 8q+1..8q+8,
// local steps j=1..8 with l_j = 1-m_j.  With s_j = v_j . h_{j-1}:
//   s_j = P_j + d_j - sum_{k<j} c_jk s_k
//   P_j = v_j . h0g_j,  h0g_j = (prod_{i<j} l_i) (.) h_0   (scan computes)
//   c_jk = v_j . [(prod_{i=k}^{j-1} l_i) (.) v_k]
//   d_j  = v_j . B_j,  B_j = sum_{k<j} (prod_{i=k+1}^{j-1} l_i) (.) m_k x_k
// All fp32 from the same bf16 v,m,x the scan reads -> identities hold to
// fp32 rounding; no rounded-w coupling needed.
// One wave per block, 32 ch/lane processed in 4 chunks of 8.
// cf layout (9 float4 per block):
//   f0 {c21,c31,c32,c41} f1 {c42,c43,c51,c52} f2 {c53,c54,c61,c62}
//   f3 {c63,c64,c65,c71} f4 {c72,c73,c74,c75} f5 {c76,c81,c82,c83}
//   f6 {c84,c85,c86,c87} f7 {d2,d3,d4,d5}     f8 {d6,d7,d8,0}
// ---------------------------------------------------------------------------
__global__ __launch_bounds__(256)
void blockprep_kernel(const u16* __restrict__ vs, const u16* __restrict__ mb,
                      const u16* __restrict__ xi, float4* __restrict__ cf)
{
  const int r = blockIdx.x * 4 + (threadIdx.x >> 6);
  const int lane = threadIdx.x & 63;
  const int b = r >> 8;              // BSLOT = 256
  const int q = r & (BSLOT - 1);
  if (q >= NBLK) return;
  const size_t e = ((size_t)b * TLEN + 8 * q + 1) * D_INNER + (size_t)lane * 32;

  float cacc[8][8];   // cacc[jj][k] = c_{jj+1,k+1}, jj=1..7, k<jj
  float dacc[8];      // dacc[jj] = d_{jj+1}, jj=1..7
#pragma unroll
  for (int j = 0; j < 8; ++j) {
    dacc[j] = 0.f;
#pragma unroll
    for (int k = 0; k < 8; ++k) cacc[j][k] = 0.f;
  }

#pragma unroll
  for (int i = 0; i < 4; ++i) {      // channel chunk: 8 ch
    float a[7][8];                   // a[k][ch]
    float B[8], pl[8], py[8];
#pragma unroll
    for (int ch = 0; ch < 8; ++ch) B[ch] = 0.f;
#pragma unroll
    for (int jj = 0; jj < 8; ++jj) { // step j = jj+1
      const size_t o = e + (size_t)jj * D_INNER + i * 8;
      const uint4 vq = *(const uint4*)(vs + o);
      const uint4 mq = *(const uint4*)(mb + o);
      const uint4 xq = *(const uint4*)(xi + o);
      const unsigned vw[4] = {vq.x, vq.y, vq.z, vq.w};
      const unsigned mw[4] = {mq.x, mq.y, mq.z, mq.w};
      const unsigned xw[4] = {xq.x, xq.y, xq.z, xq.w};
      float vf[8], mf[8], xf[8], lf[8];
#pragma unroll
      for (int k = 0; k < 4; ++k) {
        vf[2*k] = blo(vw[k]); vf[2*k+1] = bhi(vw[k]);
        mf[2*k] = blo(mw[k]); mf[2*k+1] = bhi(mw[k]);
        xf[2*k] = blo(xw[k]); xf[2*k+1] = bhi(xw[k]);
        lf[2*k] = 1.f - mf[2*k]; lf[2*k+1] = 1.f - mf[2*k+1];
      }
      if (jj > 0) {
        float dd = 0.f;
#pragma unroll
        for (int ch = 0; ch < 8; ++ch) {
          B[ch] = __builtin_fmaf(pl[ch], B[ch], py[ch]);
          dd = __builtin_fmaf(vf[ch], B[ch], dd);
        }
        dacc[jj] += dd;
#pragma unroll
        for (int k = 0; k < jj; ++k) {
          float cc = 0.f;
#pragma unroll
          for (int ch = 0; ch < 8; ++ch)
            cc = __builtin_fmaf(vf[ch], a[k][ch], cc);
          cacc[jj][k] += cc;
#pragma unroll
          for (int ch = 0; ch < 8; ++ch) a[k][ch] *= lf[ch];
        }
      }
      if (jj < 7) {
#pragma unroll
        for (int ch = 0; ch < 8; ++ch) a[jj][ch] = lf[ch] * vf[ch];
      }
#pragma unroll
      for (int ch = 0; ch < 8; ++ch) { pl[ch] = lf[ch]; py[ch] = mf[ch] * xf[ch]; }
    }
  }

#pragma unroll
  for (int jj = 1; jj < 8; ++jj) {
    dacc[jj] = wave_sum_dpp(dacc[jj]);
#pragma unroll
    for (int k = 0; k < jj; ++k) cacc[jj][k] = wave_sum_dpp(cacc[jj][k]);
  }
  if (lane == 63) {
    float4* o = cf + (size_t)r * 9;
    float4 f;
    f.x = cacc[1][0]; f.y = cacc[2][0]; f.z = cacc[2][1]; f.w = cacc[3][0]; o[0] = f;
    f.x = cacc[3][1]; f.y = cacc[3][2]; f.z = cacc[4][0]; f.w = cacc[4][1]; o[1] = f;
    f.x = cacc[4][2]; f.y = cacc[4][3]; f.z = cacc[5][0]; f.w = cacc[5][1]; o[2] = f;
    f.x = cacc[5][2]; f.y = cacc[5][3]; f.z = cacc[5][4]; f.w = cacc[6][0]; o[3] = f;
    f.x = cacc[6][1]; f.y = cacc[6][2]; f.z = cacc[6][3]; f.w = cacc[6][4]; o[4] = f;
    f.x = cacc[6][5]; f.y = cacc[7][0]; f.z = cacc[7][1]; f.w = cacc[7][2]; o[5] = f;
    f.x = cacc[7][3]; f.y = cacc[7][4]; f.z = cacc[7][5]; f.w = cacc[7][6]; o[6] = f;
    f.x = dacc[1];    f.y = dacc[2];    f.z = dacc[3];    f.w = dacc[4];    o[7] = f;
    f.x = dacc[5];    f.y = dacc[6];    f.z = dacc[7];    f.w = 0.f;        o[8] = f;
  }
}

// gh <- sz * gh  elementwise (full chip), in-place over the h buffer
__global__ void zmul_kernel(u16* __restrict__ gh, const u16* __restrict__ sz, int n8)
{
  const int i = blockIdx.x * blockDim.x + threadIdx.x;
  if (i >= n8) return;
  const uint4 hv = ((const uint4*)gh)[i];
  const uint4 zv = ((const uint4*)sz)[i];
  const unsigned hw[4] = {hv.x, hv.y, hv.z, hv.w};
  const unsigned zw[4] = {zv.x, zv.y, zv.z, zv.w};
  unsigned ow[4];
#pragma unroll
  for (int q = 0; q < 4; ++q)
    ow[q] = pkbf(blo(zw[q]) * blo(hw[q]), bhi(zw[q]) * bhi(hw[q]));
  uint4 o; o.x = ow[0]; o.y = ow[1]; o.z = ow[2]; o.w = ow[3];
  ((uint4*)gh)[i] = o;
}

// ---------------------------------------------------------------------------
// G=8 block scan: 256 thr (4 waves), 8 ch/thread, ONE barrier round per 8
// timesteps. Diet bytes (v,x,m bf16 = 48 B/step/thread), h0g maintained
// in-register. Prefetch: separate-struct + sched_barrier (verified), depth 1
// (round ~2.5k cy >> load latency), 33 loads per clump -> deep vmem pipeline.
// ---------------------------------------------------------------------------
struct Blk {
  uint4 v[8], x[8], m[8];
  float4 c[9];
};

__global__ __launch_bounds__(256, 1)
void scan8_kernel(const u16* __restrict__ xi, const u16* __restrict__ vs,
                  const u16* __restrict__ mb, const float4* __restrict__ cf,
                  u16* __restrict__ hb)
{
  const int b = blockIdx.x, tid = threadIdx.x;
  const int wave = tid >> 6, lane = tid & 63;
  const size_t base = (size_t)b * TLEN * D_INNER + (size_t)tid * 8;
  __shared__ __attribute__((aligned(16))) float sS[2][8][4];

  auto load_blk = [&](int q) {
    Blk p;
    const size_t e1 = base + (size_t)(8 * q + 1) * D_INNER;
#pragma unroll
    for (int j = 0; j < 8; ++j) {
      p.v[j] = *(const uint4*)(vs + e1 + (size_t)j * D_INNER);
      p.x[j] = *(const uint4*)(xi + e1 + (size_t)j * D_INNER);
      p.m[j] = *(const uint4*)(mb + e1 + (size_t)j * D_INNER);
    }
    const float4* cp = cf + (size_t)(b * BSLOT + q) * 9;
#pragma unroll
    for (int i = 0; i < 9; ++i) p.c[i] = cp[i];
    return p;
  };

  float h[8];
  {  // t = 0: h = xi (exact bf16 copy)
    const uint4 x0 = *(const uint4*)(xi + base);
    const unsigned xw[4] = {x0.x, x0.y, x0.z, x0.w};
#pragma unroll
    for (int p = 0; p < 4; ++p) {
      h[2*p]   = blo(xw[p]);
      h[2*p+1] = bhi(xw[p]);
    }
    *(uint4*)(hb + base) = x0;
  }

  auto round = [&](const Blk& p, int q) {
    const int par = q & 1;
    // ---- dot phase: P_j = v_j . h0g, then h0g *= l_j ----
    float h0g[8];
#pragma unroll
    for (int k = 0; k < 8; ++k) h0g[k] = h[k];
    float P[8];
#pragma unroll
    for (int j = 0; j < 8; ++j) {
      const unsigned vw[4] = {p.v[j].x, p.v[j].y, p.v[j].z, p.v[j].w};
      float a0 = 0.f, a1 = 0.f;
#pragma unroll
      for (int k = 0; k < 4; ++k) {
        a0 = __builtin_fmaf(blo(vw[k]), h0g[2*k],   a0);
        a1 = __builtin_fmaf(bhi(vw[k]), h0g[2*k+1], a1);
      }
      P[j] = a0 + a1;
      if (j < 7) {
        const unsigned mw[4] = {p.m[j].x, p.m[j].y, p.m[j].z, p.m[j].w};
#pragma unroll
        for (int k = 0; k < 4; ++k) {
          h0g[2*k]   *= (1.f - blo(mw[k]));
          h0g[2*k+1] *= (1.f - bhi(mw[k]));
        }
      }
    }
#pragma unroll
    for (int j = 0; j < 8; ++j) {
      P[j] = wave_sum_dpp(P[j]);
      if (lane == 63) sS[par][j][wave] = P[j];
    }
    asm volatile("s_waitcnt lgkmcnt(0)\n\ts_barrier" ::: "memory");
    float S[8];
#pragma unroll
    for (int j = 0; j < 8; ++j) {
      const float4 sp = *(const float4*)&sS[par][j][0];
      S[j] = (sp.x + sp.y) + (sp.z + sp.w);
    }
    // ---- triangular solve ----
    const float c21 = p.c[0].x, c31 = p.c[0].y, c32 = p.c[0].z, c41 = p.c[0].w;
    const float c42 = p.c[1].x, c43 = p.c[1].y, c51 = p.c[1].z, c52 = p.c[1].w;
    const float c53 = p.c[2].x, c54 = p.c[2].y, c61 = p.c[2].z, c62 = p.c[2].w;
    const float c63 = p.c[3].x, c64 = p.c[3].y, c65 = p.c[3].z, c71 = p.c[3].w;
    const float c72 = p.c[4].x, c73 = p.c[4].y, c74 = p.c[4].z, c75 = p.c[4].w;
    const float c76 = p.c[5].x, c81 = p.c[5].y, c82 = p.c[5].z, c83 = p.c[5].w;
    const float c84 = p.c[6].x, c85 = p.c[6].y, c86 = p.c[6].z, c87 = p.c[6].w;
    const float d2 = p.c[7].x, d3 = p.c[7].y, d4 = p.c[7].z, d5 = p.c[7].w;
    const float d6 = p.c[8].x, d7 = p.c[8].y, d8 = p.c[8].z;
    float sv[8];
    sv[0] = S[0];
    sv[1] = __builtin_fmaf(-c21, sv[0], S[1] + d2);
    sv[2] = __builtin_fmaf(-c32, sv[1], __builtin_fmaf(-c31, sv[0], S[2] + d3));
    sv[3] = __builtin_fmaf(-c43, sv[2], __builtin_fmaf(-c42, sv[1],
              __builtin_fmaf(-c41, sv[0], S[3] + d4)));
    sv[4] = __builtin_fmaf(-c54, sv[3], __builtin_fmaf(-c53, sv[2],
              __builtin_fmaf(-c52, sv[1], __builtin_fmaf(-c51, sv[0], S[4] + d5))));
    sv[5] = __builtin_fmaf(-c65, sv[4], __builtin_fmaf(-c64, sv[3],
              __builtin_fmaf(-c63, sv[2], __builtin_fmaf(-c62, sv[1],
              __builtin_fmaf(-c61, sv[0], S[5] + d6)))));
    sv[6] = __builtin_fmaf(-c76, sv[5], __builtin_fmaf(-c75, sv[4],
              __builtin_fmaf(-c74, sv[3], __builtin_fmaf(-c73, sv[2],
              __builtin_fmaf(-c72, sv[1], __builtin_fmaf(-c71, sv[0], S[6] + d7))))));
    sv[7] = __builtin_fmaf(-c87, sv[6], __builtin_fmaf(-c86, sv[5],
              __builtin_fmaf(-c85, sv[4], __builtin_fmaf(-c84, sv[3],
              __builtin_fmaf(-c83, sv[2], __builtin_fmaf(-c82, sv[1],
              __builtin_fmaf(-c81, sv[0], S[7] + d8)))))));
    // ---- update phase: h_j = (h-v s) + m (x - (h-v s)) ----
    const size_t e1 = base + (size_t)(8 * q + 1) * D_INNER;
#pragma unroll
    for (int j = 0; j < 8; ++j) {
      const unsigned vw[4] = {p.v[j].x, p.v[j].y, p.v[j].z, p.v[j].w};
      const unsigned mw[4] = {p.m[j].x, p.m[j].y, p.m[j].z, p.m[j].w};
      const unsigned xw[4] = {p.x[j].x, p.x[j].y, p.x[j].z, p.x[j].w};
      unsigned ow[4];
#pragma unroll
      for (int k = 0; k < 4; ++k) {
        const float X0 = blo(xw[k]), X1 = bhi(xw[k]);
        const float t0 = __builtin_fmaf(blo(vw[k]), -sv[j], h[2*k]);
        const float t1 = __builtin_fmaf(bhi(vw[k]), -sv[j], h[2*k+1]);
        h[2*k]   = __builtin_fmaf(blo(mw[k]), X0 - t0, t0);
        h[2*k+1] = __builtin_fmaf(bhi(mw[k]), X1 - t1, t1);
        ow[k] = pkbf(h[2*k], h[2*k+1]);
      }
      uint4 o; o.x = ow[0]; o.y = ow[1]; o.z = ow[2]; o.w = ow[3];
      *(uint4*)(hb + e1 + (size_t)j * D_INNER) = o;
    }
  };

  auto solo = [&](int t, int par) {
    const size_t o = base + (size_t)t * D_INNER;
    const uint4 vv = *(const uint4*)(vs + o);
    const uint4 xv = *(const uint4*)(xi + o);
    const uint4 mv = *(const uint4*)(mb + o);
    const unsigned vw[4] = {vv.x, vv.y, vv.z, vv.w};
    float P0 = 0.f, P1 = 0.f;
#pragma unroll
    for (int k = 0; k < 4; ++k) {
      P0 = __builtin_fmaf(blo(vw[k]), h[2*k],   P0);
      P1 = __builtin_fmaf(bhi(vw[k]), h[2*k+1], P1);
    }
    float P = wave_sum_dpp(P0 + P1);
    if (lane == 63) sS[par][0][wave] = P;
    asm volatile("s_waitcnt lgkmcnt(0)\n\ts_barrier" ::: "memory");
    const float4 sp = *(const float4*)&sS[par][0][0];
    const float s = (sp.x + sp.y) + (sp.z + sp.w);
    const unsigned xw[4] = {xv.x, xv.y, xv.z, xv.w};
    const unsigned mw[4] = {mv.x, mv.y, mv.z, mv.w};
    unsigned ow[4];
#pragma unroll
    for (int k = 0; k < 4; ++k) {
      const float X0 = blo(xw[k]), X1 = bhi(xw[k]);
      const float t0 = __builtin_fmaf(blo(vw[k]), -s, h[2*k]);
      const float t1 = __builtin_fmaf(bhi(vw[k]), -s, h[2*k+1]);
      h[2*k]   = __builtin_fmaf(blo(mw[k]), X0 - t0, t0);
      h[2*k+1] = __builtin_fmaf(bhi(mw[k]), X1 - t1, t1);
      ow[k] = pkbf(h[2*k], h[2*k+1]);
    }
    uint4 ov; ov.x = ow[0]; ov.y = ow[1]; ov.z = ow[2]; ov.w = ow[3];
    *(uint4*)(hb + o) = ov;
  };

  // depth-1 software pipeline; sched_barrier(0) pins each load clump
  Blk A = load_blk(0);
  __builtin_amdgcn_sched_barrier(0);
  for (int q = 0; q < NBLK - 1; ++q) {
    Blk N = load_blk(q + 1);
    __builtin_amdgcn_sched_barrier(0);
    round(A, q);
    A = N;
  }
  round(A, NBLK - 1);
  // tail t = 2041..2047 (7 solos), parity alternating from 1
  solo(2041, 1); solo(2042, 0); solo(2043, 1); solo(2044, 0);
  solo(2045, 1); solo(2046, 0); solo(2047, 1);
}

extern "C" void kernel_launch(void* const* d_in, const int* in_sizes, int n_in,
                              void* d_out, int out_size, void* d_ws, size_t ws_size,
                              hipStream_t stream)
{
  const float* x     = (const float*)d_in[0];
  const float* omega = (const float*)d_in[1];
  const float* Win   = (const float*)d_in[2];
  const float* Wl    = (const float*)d_in[3];
  const float* bl    = (const float*)d_in[4];
  const float* Wv    = (const float*)d_in[5];
  const float* bv    = (const float*)d_in[6];
  const float* Wout  = (const float*)d_in[7];
  float* out = (float*)d_out;
  (void)in_sizes; (void)n_in; (void)out_size; (void)ws_size;

  size_t off = 0;
  auto carve = [&](size_t bytes) -> void* {
    void* r = (char*)d_ws + off;
    off += (bytes + 255) & ~(size_t)255;
    return r;
  };
  u16*  x_bf    = (u16*)carve((size_t)BT * D_MODEL * 2);          // dead after gemm<0>
  u16*  Win_bf  = (u16*)carve((size_t)2 * D_INNER * D_MODEL * 2);
  u16*  Wl_bf   = (u16*)carve((size_t)D_INNER * D_INNER * 2);
  u16*  Wv_bf   = (u16*)carve((size_t)D_INNER * D_INNER * 2);
  u16*  Wout_bf = (u16*)carve((size_t)D_MODEL * D_INNER * 2);
  u16*  xi_bf   = (u16*)carve((size_t)BT * D_INNER * 2);
  u16*  sz_bf   = (u16*)carve((size_t)BT * D_INNER * 2);
  u16*  v_bf    = (u16*)carve((size_t)BT * D_INNER * 2);
  u16*  gh_bf   = (u16*)carve((size_t)BT * D_INNER * 2);   // scan h, then z*h in-place
  u16*  mb      = (u16*)carve((size_t)BT * D_INNER * 2);   // 1-lam, bf16
  float* sfac   = (float*)carve((size_t)D_INNER * 4);
  float4* cf    = (float4*)carve((size_t)NBATCH * BSLOT * 9 * 16);

  conv_bf16_kernel<<<(BT * D_MODEL / 4 + 255) / 256, 256, 0, stream>>>(x, x_bf, BT * D_MODEL / 4);
  conv_bf16_kernel<<<(2 * D_INNER * D_MODEL / 4 + 255) / 256, 256, 0, stream>>>(Win, Win_bf, 2 * D_INNER * D_MODEL / 4);
  conv_bf16_kernel<<<(D_INNER * D_INNER / 4 + 255) / 256, 256, 0, stream>>>(Wl, Wl_bf, D_INNER * D_INNER / 4);
  conv_bf16_kernel<<<(D_INNER * D_INNER / 4 + 255) / 256, 256, 0, stream>>>(Wv, Wv_bf, D_INNER * D_INNER / 4);
  conv_bf16_kernel<<<(D_MODEL * D_INNER / 4 + 255) / 256, 256, 0, stream>>>(Wout, Wout_bf, D_MODEL * D_INNER / 4);
  sfac_kernel<<<(D_INNER + 255) / 256, 256, 0, stream>>>(omega, sfac);

  // xz = x @ Win^T  -> xi (bf16) | silu(z) (bf16)
  gemm_nt<0><<<dim3(4096 / 128, BT / 128), 256, 0, stream>>>(
      x_bf, Win_bf, BT, 4096, D_MODEL, nullptr, xi_bf, sz_bf, nullptr, nullptr, nullptr);
  // merged: mb = bf16(1-lam) | v = xi@Wv^T+bv bf16
  gemm_nt<4><<<dim3(4096 / 128, BT / 128), 256, 0, stream>>>(
      xi_bf, Wl_bf, BT, 4096, D_INNER, nullptr, v_bf, mb, bl, sfac, bv);
  // v <- v*sqrt(2/(v.v))
  vscale_kernel<<<BT / 4, 256, 0, stream>>>(v_bf);
  // block cross-terms cf (28 c + 7 d per block of 8)
  blockprep_kernel<<<NBATCH * BSLOT / 4, 256, 0, stream>>>(v_bf, mb, xi_bf, cf);
  // G=8 block scan -> hb = h (bf16)
  scan8_kernel<<<NBATCH, 256, 0, stream>>>(xi_bf, v_bf, mb, cf, gh_bf);
  // gh = silu(z)*h (full chip, in-place)
  zmul_kernel<<<(BT * D_INNER / 8 + 255) / 256, 256, 0, stream>>>(gh_bf, sz_bf, BT * D_INNER / 8);
  // out = gh @ Wout^T (fp32)
  gemm_nt<3><<<dim3(D_MODEL / 128, BT / 128), 256, 0, stream>>>(
      gh_bf, Wout_bf, BT, D_MODEL, D_INNER, out, nullptr, nullptr, nullptr, nullptr, nullptr);
}

// Round 6
// 1163.970 us; speedup vs baseline: 1.0757x; 1.0757x over previous
//
#include <hip/hip_runtime.h>
#include <cstdint>
#include <cstddef>

typedef unsigned short u16;
typedef __attribute__((ext_vector_type(8))) short s8v;   // 8 bf16 in 4 VGPRs
typedef __attribute__((ext_vector_type(4))) float f4v;   // MFMA accumulator
typedef __attribute__((ext_vector_type(2))) float f32x2;
typedef __attribute__((ext_vector_type(2))) unsigned u32x2;

#define D_MODEL 1024
#define D_INNER 2048
#define BT      8192   // B*T
#define TLEN    2048
#define NBATCH  4

struct alignas(8) U16x4 { u16 x, y, z, w; };

__device__ __forceinline__ u16 f2bf(float f) {
  union { float f; unsigned u; } c; c.f = f;
  unsigned r = c.u + 0x7FFFu + ((c.u >> 16) & 1u);   // RNE
  return (u16)(r >> 16);
}
// bf16 unpack from packed pair (u32): low ch / high ch
__device__ __forceinline__ float blo(unsigned u) {
  union { unsigned u; float f; } c; c.u = u << 16; return c.f;
}
__device__ __forceinline__ float bhi(unsigned u) {
  union { unsigned u; float f; } c; c.u = u & 0xffff0000u; return c.f;
}
// pack two fp32 -> packed bf16 pair (round half up), lo in low 16
__device__ __forceinline__ unsigned pkbf(float lo, float hi) {
  union { float f; unsigned u; } a, b; a.f = lo; b.f = hi;
#if __has_builtin(__builtin_amdgcn_perm)
  return __builtin_amdgcn_perm(b.u + 0x8000u, a.u + 0x8000u, 0x07060302u);
#else
  return ((b.u + 0x8000u) & 0xffff0000u) | ((a.u + 0x8000u) >> 16);
#endif
}

// DPP wave-64 sum: VALU-pipe latency instead of ds_bpermute. Result in lane 63.
#define DPPADD(x, ctrl) \
  ((x) + __builtin_bit_cast(float, __builtin_amdgcn_update_dpp( \
       0, __builtin_bit_cast(int, (x)), (ctrl), 0xF, 0xF, true)))
__device__ __forceinline__ float wave_sum_dpp(float x) {
  x = DPPADD(x, 0x111);  // row_shr:1
  x = DPPADD(x, 0x112);  // row_shr:2
  x = DPPADD(x, 0x114);  // row_shr:4
  x = DPPADD(x, 0x118);  // row_shr:8
  x = DPPADD(x, 0x142);  // row_bcast:15
  x = DPPADD(x, 0x143);  // row_bcast:31
  return x;              // lane 63 = wave sum
}

// async global->LDS, 16B per lane; LDS dest must be wave-uniform base (+lane*16 by HW)
__device__ __forceinline__ void glds16(const u16* g, const u16* lds) {
  __builtin_amdgcn_global_load_lds(
      (const __attribute__((address_space(1))) unsigned int*)(uintptr_t)g,
      (__attribute__((address_space(3))) unsigned int*)(unsigned int)(uintptr_t)lds,
      16, 0, 0);
}

// ---------------------------------------------------------------------------
// GEMM (unchanged, round-4 verified). EPI 0 / 4 / 3 as before.
// ---------------------------------------------------------------------------
template<int EPI>
__global__ __launch_bounds__(256, 2)
void gemm_nt(const u16* __restrict__ A, const u16* __restrict__ B,
             int M, int N, int K,
             float* __restrict__ Cf, u16* __restrict__ Cb, u16* __restrict__ Cb2,
             const float* __restrict__ bias, const float* __restrict__ sfac,
             const float* __restrict__ bias2)
{
  __shared__ u16 lA[128 * 32];
  __shared__ u16 lB[128 * 32];
  const int tid  = threadIdx.x;
  const int wave = tid >> 6, lane = tid & 63;
  const int wm = wave >> 1, wn = wave & 1;
  const int bm0 = blockIdx.y * 128, bn0 = blockIdx.x * 128;

  const int srow = lane >> 2;
  const int scol = (lane & 3) * 8;
  const u16* pa0 = A + (size_t)(bm0 + wave * 32 + srow) * K + scol;
  const u16* pa1 = pa0 + (size_t)16 * K;
  const u16* pb0 = B + (size_t)(bn0 + wave * 32 + srow) * K + scol;
  const u16* pb1 = pb0 + (size_t)16 * K;
  u16* la0 = lA + (wave * 32) * 32;
  u16* la1 = la0 + 16 * 32;
  u16* lb0 = lB + (wave * 32) * 32;
  u16* lb1 = lb0 + 16 * 32;

  const int fr = lane & 15, kq = lane >> 4;
  const u16* fA = lA + (wm * 64 + fr) * 32 + kq * 8;
  const u16* fB = lB + (wn * 64 + fr) * 32 + kq * 8;

  f4v acc[4][4];
  const f4v zf = {0.f, 0.f, 0.f, 0.f};
  for (int i = 0; i < 4; ++i)
    for (int j = 0; j < 4; ++j)
      acc[i][j] = zf;

  for (int k0 = 0; k0 < K; k0 += 32) {
    glds16(pa0 + k0, la0);
    glds16(pa1 + k0, la1);
    glds16(pb0 + k0, lb0);
    glds16(pb1 + k0, lb1);
    __syncthreads();
    s8v af[4], bfv[4];
#pragma unroll
    for (int i = 0; i < 4; ++i) af[i] = *(const s8v*)(fA + i * 16 * 32);
#pragma unroll
    for (int j = 0; j < 4; ++j) bfv[j] = *(const s8v*)(fB + j * 16 * 32);
#pragma unroll
    for (int i = 0; i < 4; ++i)
#pragma unroll
      for (int j = 0; j < 4; ++j)
        acc[i][j] = __builtin_amdgcn_mfma_f32_16x16x32_bf16(af[i], bfv[j], acc[i][j], 0, 0, 0);
    __syncthreads();
  }

  // C/D layout: col = lane&15, row = (lane>>4)*4 + reg
#pragma unroll
  for (int i = 0; i < 4; ++i) {
#pragma unroll
    for (int j = 0; j < 4; ++j) {
#pragma unroll
      for (int r = 0; r < 4; ++r) {
        const int gm = bm0 + wm * 64 + i * 16 + kq * 4 + r;
        const int gn = bn0 + wn * 64 + j * 16 + fr;
        const float val = acc[i][j][r];
        if (EPI == 0) {
          if (gn < D_INNER) {
            Cb[(size_t)gm * D_INNER + gn] = f2bf(val);
          } else {
            const float s = val / (1.f + __expf(-val));  // silu(z)
            Cb2[(size_t)gm * D_INNER + (gn - D_INNER)] = f2bf(s);
          }
        } else if (EPI == 4) {
          if (gn < D_INNER) {
            const float pre = val + bias[gn];
            const float sig = 1.f / (1.f + __expf(-pre));
            const float m = -expm1f(sfac[gn] * sig);   // 1 - lam, full precision
            Cb2[(size_t)gm * D_INNER + gn] = f2bf(m);
          } else {
            Cb[(size_t)gm * D_INNER + (gn - D_INNER)] = f2bf(val + bias2[gn - D_INNER]);
          }
        } else {
          Cf[(size_t)gm * N + gn] = val;
        }
      }
    }
  }
}

// ---------------------------------------------------------------------------
// Fused bf16 conversion of all 5 inputs in ONE launch. The 5 output regions
// are contiguous in the workspace carve (all sizes 256B-aligned):
//   [x | Win | Wl | Wv | Wout], float4-unit boundaries below.
// ---------------------------------------------------------------------------
#define CV_R0 2097152   // x end        (8192*1024/4)
#define CV_R1 3145728   // Win end      (+4096*1024/4)
#define CV_R2 4194304   // Wl end       (+2048*2048/4)
#define CV_R3 5242880   // Wv end
#define CV_R4 5767168   // Wout end     (+1024*2048/4)  == grid*256 exactly

__global__ __launch_bounds__(256)
void convall_kernel(const float* __restrict__ x, const float* __restrict__ Win,
                    const float* __restrict__ Wl, const float* __restrict__ Wv,
                    const float* __restrict__ Wout, u16* __restrict__ outb)
{
  const int g = blockIdx.x * 256 + threadIdx.x;   // float4 index, < CV_R4
  const float* in; int lo;
  if (g < CV_R0)      { in = x;    lo = g; }
  else if (g < CV_R1) { in = Win;  lo = g - CV_R0; }
  else if (g < CV_R2) { in = Wl;   lo = g - CV_R1; }
  else if (g < CV_R3) { in = Wv;   lo = g - CV_R2; }
  else                { in = Wout; lo = g - CV_R3; }
  const float4 v = ((const float4*)in)[lo];
  U16x4 o; o.x = f2bf(v.x); o.y = f2bf(v.y); o.z = f2bf(v.z); o.w = f2bf(v.w);
  ((U16x4*)outb)[g] = o;
}

__global__ void sfac_kernel(const float* __restrict__ omega, float* __restrict__ sfac)
{
  const int i = blockIdx.x * blockDim.x + threadIdx.x;
  if (i < D_INNER) sfac[i] = -8.f * log1pf(expf(omega[i]));  // -C*softplus(omega)
}

// v <- v * sqrt(2/(v.v)) per row; 1 wave per row, 4 rows per block.
__global__ __launch_bounds__(256)
void vscale_kernel(u16* __restrict__ v)
{
  const int row  = blockIdx.x * 4 + (threadIdx.x >> 6);
  const int lane = threadIdx.x & 63;
  uint4* p = (uint4*)(v + (size_t)row * D_INNER + lane * 32);  // 32 ch/lane
  uint4 a[4];
#pragma unroll
  for (int i = 0; i < 4; ++i) a[i] = p[i];
  float s = 0.f;
#pragma unroll
  for (int i = 0; i < 4; ++i) {
    const unsigned w[4] = {a[i].x, a[i].y, a[i].z, a[i].w};
#pragma unroll
    for (int j = 0; j < 4; ++j) {
      const float f0 = blo(w[j]), f1 = bhi(w[j]);
      s += f0 * f0 + f1 * f1;
    }
  }
  s += __shfl_down(s, 32); s += __shfl_down(s, 16); s += __shfl_down(s, 8);
  s += __shfl_down(s, 4);  s += __shfl_down(s, 2);  s += __shfl_down(s, 1);
  const float sc = sqrtf(2.f / __shfl(s, 0));
#pragma unroll
  for (int i = 0; i < 4; ++i) {
    const unsigned w[4] = {a[i].x, a[i].y, a[i].z, a[i].w};
    unsigned o[4];
#pragma unroll
    for (int j = 0; j < 4; ++j) o[j] = pkbf(blo(w[j]) * sc, bhi(w[j]) * sc);
    uint4 ov; ov.x = o[0]; ov.y = o[1]; ov.z = o[2]; ov.w = o[3];
    p[i] = ov;
  }
}

// Pair precompute (round-4 verified), one wave per even t:
//   C1_t = (v_{t+1} - v_{t+1}*m_t) . v_t ;  C2_t = v_{t+1} . (m_t * x_t)
__global__ __launch_bounds__(256)
void pairprep_kernel(const u16* __restrict__ vs, const u16* __restrict__ mb,
                     const u16* __restrict__ xi, f32x2* __restrict__ C12)
{
  const int r = blockIdx.x * 4 + (threadIdx.x >> 6);  // r = b*1024 + t/2
  const int lane = threadIdx.x & 63;
  const int b = r >> 10;
  const int t = (r & 1023) * 2;
  const size_t o0 = ((size_t)b * TLEN + t) * D_INNER + (size_t)lane * 32;
  const size_t o1 = o0 + D_INNER;
  const uint4* pv0 = (const uint4*)(vs + o0);
  const uint4* pv1 = (const uint4*)(vs + o1);
  const uint4* px0 = (const uint4*)(xi + o0);
  const uint4* pm0 = (const uint4*)(mb + o0);
  float c1 = 0.f, c2 = 0.f;
#pragma unroll
  for (int i = 0; i < 4; ++i) {
    const uint4 v0 = pv0[i], v1 = pv1[i], x0 = px0[i], m0 = pm0[i];
    const unsigned v0w[4] = {v0.x, v0.y, v0.z, v0.w};
    const unsigned v1w[4] = {v1.x, v1.y, v1.z, v1.w};
    const unsigned x0w[4] = {x0.x, x0.y, x0.z, x0.w};
    const unsigned m0w[4] = {m0.x, m0.y, m0.z, m0.w};
#pragma unroll
    for (int q = 0; q < 4; ++q) {
      const float va = blo(v0w[q]), vb = bhi(v0w[q]);
      const float ua = blo(v1w[q]), ub = bhi(v1w[q]);
      const float xa = blo(x0w[q]), xb = bhi(x0w[q]);
      const float ma = blo(m0w[q]), mbv = bhi(m0w[q]);
      const float wa = __builtin_fmaf(-ua, ma, ua);    // v1*(1-m0), fp32
      const float wb = __builtin_fmaf(-ub, mbv, ub);
      c1 += wa * va + wb * vb;
      c2 += ua * (ma * xa) + ub * (mbv * xb);
    }
  }
  c1 = wave_sum_dpp(c1);
  c2 = wave_sum_dpp(c2);
  if (lane == 63) { f32x2 cc; cc.x = c1; cc.y = c2; C12[r] = cc; }
}

// gh <- sz * gh  elementwise (full chip), in-place over the h buffer
__global__ void zmul_kernel(u16* __restrict__ gh, const u16* __restrict__ sz, int n8)
{
  const int i = blockIdx.x * blockDim.x + threadIdx.x;
  if (i >= n8) return;
  const uint4 hv = ((const uint4*)gh)[i];
  const uint4 zv = ((const uint4*)sz)[i];
  const unsigned hw[4] = {hv.x, hv.y, hv.z, hv.w};
  const unsigned zw[4] = {zv.x, zv.y, zv.z, zv.w};
  unsigned ow[4];
#pragma unroll
  for (int q = 0; q < 4; ++q)
    ow[q] = pkbf(blo(zw[q]) * blo(hw[q]), bhi(zw[q]) * bhi(hw[q]));
  uint4 o; o.x = ow[0]; o.y = ow[1]; o.z = ow[2]; o.w = ow[3];
  ((uint4*)gh)[i] = o;
}

// ---------------------------------------------------------------------------
// Paired sequential scan — round-4 verified algebra/diet, now at 512 threads
// (8 waves, 2/SIMD) with 4 ch/thread. Same bytes, same total VALU; the second
// wave per SIMD fills the first's DPP/barrier/vmem stalls (round-4 counters
// showed VALU 650cy and mem-return 1024cy nearly ADDITIVE at 1 wave/SIMD).
// Stores are nontemporal (h never re-read by scan; spare the 4MB L2 slice).
// ---------------------------------------------------------------------------
struct Pair {
  uint2 v0, v1, x0, x1, m0, m1;
  f32x2 c;
};

__global__ __launch_bounds__(512, 1)
void scan2_kernel(const u16* __restrict__ xi, const u16* __restrict__ vs,
                  const u16* __restrict__ mb, const f32x2* __restrict__ C12,
                  u16* __restrict__ hb)
{
  const int b = blockIdx.x, tid = threadIdx.x;
  const int wave = tid >> 6, lane = tid & 63;
  const size_t base = (size_t)b * TLEN * D_INNER + (size_t)tid * 4;
  const int cb0 = b * 1024;
  __shared__ __attribute__((aligned(16))) float rP[2][8], rQ[2][8];

  auto load_pair = [&](int t) {
    Pair p;
    const size_t o0 = base + (size_t)t * D_INNER;
    const size_t o1 = o0 + D_INNER;
    p.v0 = *(const uint2*)(vs + o0);
    p.v1 = *(const uint2*)(vs + o1);
    p.x0 = *(const uint2*)(xi + o0);
    p.x1 = *(const uint2*)(xi + o1);
    p.m0 = *(const uint2*)(mb + o0);
    p.m1 = *(const uint2*)(mb + o1);
    p.c = C12[cb0 + (t >> 1)];
    return p;
  };

  float h[4];
  {  // t = 0: h = xi (exact bf16 copy)
    const uint2 x0 = *(const uint2*)(xi + base);
    h[0] = blo(x0.x); h[1] = bhi(x0.x); h[2] = blo(x0.y); h[3] = bhi(x0.y);
    u32x2 o; o.x = x0.x; o.y = x0.y;
    __builtin_nontemporal_store(o, (u32x2*)(hb + base));
  }

  {  // solo step t = 1
    const size_t o = base + D_INNER;
    const uint2 v1v = *(const uint2*)(vs + o);
    const uint2 x1v = *(const uint2*)(xi + o);
    const uint2 m1v = *(const uint2*)(mb + o);
    const unsigned vw[2] = {v1v.x, v1v.y};
    float vf[4];
    float P0 = 0.f, P1 = 0.f;
#pragma unroll
    for (int q = 0; q < 2; ++q) {
      vf[2*q]   = blo(vw[q]);
      vf[2*q+1] = bhi(vw[q]);
      P0 = __builtin_fmaf(vf[2*q],   h[2*q],   P0);
      P1 = __builtin_fmaf(vf[2*q+1], h[2*q+1], P1);
    }
    float P = wave_sum_dpp(P0 + P1);
    if (lane == 63) rP[0][wave] = P;
    asm volatile("s_waitcnt lgkmcnt(0)\n\ts_barrier" ::: "memory");
    const float4 pa = *(const float4*)&rP[0][0];
    const float4 pb = *(const float4*)&rP[0][4];
    const float a = ((pa.x + pa.y) + (pa.z + pa.w)) + ((pb.x + pb.y) + (pb.z + pb.w));
    const unsigned xw[2] = {x1v.x, x1v.y};
    const unsigned mw[2] = {m1v.x, m1v.y};
    unsigned ow[2];
#pragma unroll
    for (int q = 0; q < 2; ++q) {
      const float X0 = blo(xw[q]), X1 = bhi(xw[q]);
      const float M0 = blo(mw[q]), M1 = bhi(mw[q]);
      const float t0 = __builtin_fmaf(vf[2*q],   -a, h[2*q]);
      const float t1 = __builtin_fmaf(vf[2*q+1], -a, h[2*q+1]);
      h[2*q]   = __builtin_fmaf(M0, X0 - t0, t0);
      h[2*q+1] = __builtin_fmaf(M1, X1 - t1, t1);
      ow[q] = pkbf(h[2*q], h[2*q+1]);
    }
    u32x2 ov; ov.x = ow[0]; ov.y = ow[1];
    __builtin_nontemporal_store(ov, (u32x2*)(hb + o));
  }

  auto round = [&](const Pair& p, int t) {
    const int par = (t >> 1) & 1;
    const unsigned v0w[2] = {p.v0.x, p.v0.y};
    const unsigned v1w[2] = {p.v1.x, p.v1.y};
    const unsigned m0w[2] = {p.m0.x, p.m0.y};
    float vf[4], uf[4], mf0[4];
    float P0 = 0.f, P1 = 0.f, Q0 = 0.f, Q1 = 0.f;
#pragma unroll
    for (int q = 0; q < 2; ++q) {
      vf[2*q]   = blo(v0w[q]);
      vf[2*q+1] = bhi(v0w[q]);
      uf[2*q]   = blo(v1w[q]);
      uf[2*q+1] = bhi(v1w[q]);
      mf0[2*q]  = blo(m0w[q]);
      mf0[2*q+1]= bhi(m0w[q]);
      const float wa = __builtin_fmaf(-uf[2*q],   mf0[2*q],   uf[2*q]);   // v1*l0
      const float wb = __builtin_fmaf(-uf[2*q+1], mf0[2*q+1], uf[2*q+1]);
      P0 = __builtin_fmaf(vf[2*q],   h[2*q],   P0);
      P1 = __builtin_fmaf(vf[2*q+1], h[2*q+1], P1);
      Q0 = __builtin_fmaf(wa, h[2*q],   Q0);
      Q1 = __builtin_fmaf(wb, h[2*q+1], Q1);
    }
    float P = wave_sum_dpp(P0 + P1);
    float Q = wave_sum_dpp(Q0 + Q1);
    if (lane == 63) { rP[par][wave] = P; rQ[par][wave] = Q; }
    asm volatile("s_waitcnt lgkmcnt(0)\n\ts_barrier" ::: "memory");
    const float4 pa = *(const float4*)&rP[par][0];
    const float4 pb = *(const float4*)&rP[par][4];
    const float4 qa = *(const float4*)&rQ[par][0];
    const float4 qb = *(const float4*)&rQ[par][4];
    const float a0 = ((pa.x + pa.y) + (pa.z + pa.w)) + ((pb.x + pb.y) + (pb.z + pb.w));
    const float sQ = ((qa.x + qa.y) + (qa.z + qa.w)) + ((qb.x + qb.y) + (qb.z + qb.w));
    const float a1 = __builtin_fmaf(-a0, p.c.x, sQ + p.c.y);
    const unsigned xw0[2] = {p.x0.x, p.x0.y};
    const unsigned xw1[2] = {p.x1.x, p.x1.y};
    const unsigned m1w[2] = {p.m1.x, p.m1.y};
    unsigned ow0[2], ow1[2];
#pragma unroll
    for (int q = 0; q < 2; ++q) {
      const float A0 = blo(xw0[q]), A1 = bhi(xw0[q]);
      const float B0 = blo(xw1[q]), B1 = bhi(xw1[q]);
      const float N0 = blo(m1w[q]), N1 = bhi(m1w[q]);
      float t0 = __builtin_fmaf(vf[2*q],   -a0, h[2*q]);
      float t1 = __builtin_fmaf(vf[2*q+1], -a0, h[2*q+1]);
      t0 = __builtin_fmaf(mf0[2*q],   A0 - t0, t0);   // h_t
      t1 = __builtin_fmaf(mf0[2*q+1], A1 - t1, t1);
      ow0[q] = pkbf(t0, t1);
      const float u0 = __builtin_fmaf(uf[2*q],   -a1, t0);
      const float u1 = __builtin_fmaf(uf[2*q+1], -a1, t1);
      h[2*q]   = __builtin_fmaf(N0, B0 - u0, u0);     // h_{t+1}
      h[2*q+1] = __builtin_fmaf(N1, B1 - u1, u1);
      ow1[q] = pkbf(h[2*q], h[2*q+1]);
    }
    const size_t oo = base + (size_t)t * D_INNER;
    u32x2 o0; o0.x = ow0[0]; o0.y = ow0[1];
    u32x2 o1; o1.x = ow1[0]; o1.y = ow1[1];
    __builtin_nontemporal_store(o0, (u32x2*)(hb + oo));
    __builtin_nontemporal_store(o1, (u32x2*)(hb + oo + D_INNER));
  };

  // Software pipeline, depth = 2 rounds; sched_barrier(0) pins load clumps.
  Pair A = load_pair(2);
  __builtin_amdgcn_sched_barrier(0);
  Pair B = load_pair(4);
  __builtin_amdgcn_sched_barrier(0);
  for (int t = 2; t <= 2038; t += 4) {
    Pair An = load_pair(t + 4);
    __builtin_amdgcn_sched_barrier(0);
    round(A, t);
    A = An;
    Pair Bn = load_pair(t + 6);
    __builtin_amdgcn_sched_barrier(0);
    round(B, t + 2);
    B = Bn;
  }
  {
    Pair An = load_pair(2046);
    __builtin_amdgcn_sched_barrier(0);
    round(A, 2042);
    round(B, 2044);
    round(An, 2046);
  }
}

extern "C" void kernel_launch(void* const* d_in, const int* in_sizes, int n_in,
                              void* d_out, int out_size, void* d_ws, size_t ws_size,
                              hipStream_t stream)
{
  const float* x     = (const float*)d_in[0];
  const float* omega = (const float*)d_in[1];
  const float* Win   = (const float*)d_in[2];
  const float* Wl    = (const float*)d_in[3];
  const float* bl    = (const float*)d_in[4];
  const float* Wv    = (const float*)d_in[5];
  const float* bv    = (const float*)d_in[6];
  const float* Wout  = (const float*)d_in[7];
  float* out = (float*)d_out;
  (void)in_sizes; (void)n_in; (void)out_size; (void)ws_size;

  size_t off = 0;
  auto carve = [&](size_t bytes) -> void* {
    void* r = (char*)d_ws + off;
    off += (bytes + 255) & ~(size_t)255;
    return r;
  };
  u16*  x_bf    = (u16*)carve((size_t)BT * D_MODEL * 2);          // conv region base
  u16*  Win_bf  = (u16*)carve((size_t)2 * D_INNER * D_MODEL * 2);
  u16*  Wl_bf   = (u16*)carve((size_t)D_INNER * D_INNER * 2);
  u16*  Wv_bf   = (u16*)carve((size_t)D_INNER * D_INNER * 2);
  u16*  Wout_bf = (u16*)carve((size_t)D_MODEL * D_INNER * 2);
  u16*  xi_bf   = (u16*)carve((size_t)BT * D_INNER * 2);
  u16*  sz_bf   = (u16*)carve((size_t)BT * D_INNER * 2);
  u16*  v_bf    = (u16*)carve((size_t)BT * D_INNER * 2);
  u16*  gh_bf   = (u16*)carve((size_t)BT * D_INNER * 2);   // scan h, then z*h in-place
  u16*  mb      = (u16*)carve((size_t)BT * D_INNER * 2);   // 1-lam, bf16
  float* sfac   = (float*)carve((size_t)D_INNER * 4);
  f32x2* C12    = (f32x2*)carve((size_t)(BT / 2) * 8);

  // all 5 input conversions in one launch (outputs contiguous from x_bf)
  convall_kernel<<<CV_R4 / 256, 256, 0, stream>>>(x, Win, Wl, Wv, Wout, x_bf);
  sfac_kernel<<<(D_INNER + 255) / 256, 256, 0, stream>>>(omega, sfac);

  // xz = x @ Win^T  -> xi (bf16) | silu(z) (bf16)
  gemm_nt<0><<<dim3(4096 / 128, BT / 128), 256, 0, stream>>>(
      x_bf, Win_bf, BT, 4096, D_MODEL, nullptr, xi_bf, sz_bf, nullptr, nullptr, nullptr);
  // merged: mb = bf16(1-lam) | v = xi@Wv^T+bv bf16
  gemm_nt<4><<<dim3(4096 / 128, BT / 128), 256, 0, stream>>>(
      xi_bf, Wl_bf, BT, 4096, D_INNER, nullptr, v_bf, mb, bl, sfac, bv);
  // v <- v*sqrt(2/(v.v))
  vscale_kernel<<<BT / 4, 256, 0, stream>>>(v_bf);
  // pair cross-terms: C12 = (C1,C2)
  pairprep_kernel<<<BT / 2 / 4, 256, 0, stream>>>(v_bf, mb, xi_bf, C12);
  // paired sequential scan (512 thr) -> hb = h (bf16)
  scan2_kernel<<<NBATCH, 512, 0, stream>>>(xi_bf, v_bf, mb, C12, gh_bf);
  // gh = silu(z)*h (full chip, in-place)
  zmul_kernel<<<(BT * D_INNER / 8 + 255) / 256, 256, 0, stream>>>(gh_bf, sz_bf, BT * D_INNER / 8);
  // out = gh @ Wout^T (fp32)
  gemm_nt<3><<<dim3(D_MODEL / 128, BT / 128), 256, 0, stream>>>(
      gh_bf, Wout_bf, BT, D_MODEL, D_INNER, out, nullptr, nullptr, nullptr, nullptr, nullptr);
}

// Round 7
// 1069.917 us; speedup vs baseline: 1.1703x; 1.0879x over previous
//
#include <hip/hip_runtime.h>
#include <cstdint>
#include <cstddef>

typedef unsigned short u16;
typedef __attribute__((ext_vector_type(8))) short s8v;   // 8 bf16 in 4 VGPRs
typedef __attribute__((ext_vector_type(4))) float f4v;   // MFMA accumulator
typedef __attribute__((ext_vector_type(2))) float f32x2;

#define D_MODEL 1024
#define D_INNER 2048
#define BT      8192   // B*T
#define TLEN    2048
#define NBATCH  4

struct alignas(8) U16x4 { u16 x, y, z, w; };

__device__ __forceinline__ u16 f2bf(float f) {
  union { float f; unsigned u; } c; c.f = f;
  unsigned r = c.u + 0x7FFFu + ((c.u >> 16) & 1u);   // RNE
  return (u16)(r >> 16);
}
// bf16 unpack from packed pair (u32): low ch / high ch
__device__ __forceinline__ float blo(unsigned u) {
  union { unsigned u; float f; } c; c.u = u << 16; return c.f;
}
__device__ __forceinline__ float bhi(unsigned u) {
  union { unsigned u; float f; } c; c.u = u & 0xffff0000u; return c.f;
}
// pack two fp32 -> packed bf16 pair (round half up), lo in low 16
__device__ __forceinline__ unsigned pkbf(float lo, float hi) {
  union { float f; unsigned u; } a, b; a.f = lo; b.f = hi;
#if __has_builtin(__builtin_amdgcn_perm)
  return __builtin_amdgcn_perm(b.u + 0x8000u, a.u + 0x8000u, 0x07060302u);
#else
  return ((b.u + 0x8000u) & 0xffff0000u) | ((a.u + 0x8000u) >> 16);
#endif
}

// DPP wave-64 sum: VALU-pipe latency instead of ds_bpermute. Result in lane 63.
#define DPPADD(x, ctrl) \
  ((x) + __builtin_bit_cast(float, __builtin_amdgcn_update_dpp( \
       0, __builtin_bit_cast(int, (x)), (ctrl), 0xF, 0xF, true)))
__device__ __forceinline__ float wave_sum_dpp(float x) {
  x = DPPADD(x, 0x111);  // row_shr:1
  x = DPPADD(x, 0x112);  // row_shr:2
  x = DPPADD(x, 0x114);  // row_shr:4
  x = DPPADD(x, 0x118);  // row_shr:8
  x = DPPADD(x, 0x142);  // row_bcast:15
  x = DPPADD(x, 0x143);  // row_bcast:31
  return x;              // lane 63 = wave sum
}

// async global->LDS, 16B per lane; LDS dest must be wave-uniform base (+lane*16 by HW)
__device__ __forceinline__ void glds16(const u16* g, const u16* lds) {
  __builtin_amdgcn_global_load_lds(
      (const __attribute__((address_space(1))) unsigned int*)(uintptr_t)g,
      (__attribute__((address_space(3))) unsigned int*)(unsigned int)(uintptr_t)lds,
      16, 0, 0);
}

// ---------------------------------------------------------------------------
// GEMM (round-4 verified structure) + T1 XCD-aware swizzle: consecutive
// tile indices (sharing an A-panel) are grouped onto one XCD's L2 instead of
// round-robined across 8 XCDs. nwg is 2048/2048/512 here — all %8==0, so the
// simple (w%8)*(nwg/8)+(w/8) remap is bijective.
// EPI 0: Cb=xi bf16 | Cb2=silu(z) bf16 (N split at 2048)
// EPI 4: Cb2=bf16(1-lam)=bf16(-expm1(sfac*sigmoid(acc+bias))) | Cb=v bf16
// EPI 3: Cf = acc (fp32)
// ---------------------------------------------------------------------------
template<int EPI>
__global__ __launch_bounds__(256, 2)
void gemm_nt(const u16* __restrict__ A, const u16* __restrict__ B,
             int M, int N, int K,
             float* __restrict__ Cf, u16* __restrict__ Cb, u16* __restrict__ Cb2,
             const float* __restrict__ bias, const float* __restrict__ sfac,
             const float* __restrict__ bias2)
{
  __shared__ u16 lA[128 * 32];
  __shared__ u16 lB[128 * 32];
  const int tid  = threadIdx.x;
  const int wave = tid >> 6, lane = tid & 63;
  const int wm = wave >> 1, wn = wave & 1;

  // XCD swizzle on the flattened workgroup index (gridDim.x is 32 or 8: pow2)
  const int nwg = (int)(gridDim.x * gridDim.y);
  int wg = (int)(blockIdx.y * gridDim.x + blockIdx.x);
  wg = (wg & 7) * (nwg >> 3) + (wg >> 3);
  const int bm0 = (wg / (int)gridDim.x) * 128;
  const int bn0 = (wg % (int)gridDim.x) * 128;

  const int srow = lane >> 2;
  const int scol = (lane & 3) * 8;
  const u16* pa0 = A + (size_t)(bm0 + wave * 32 + srow) * K + scol;
  const u16* pa1 = pa0 + (size_t)16 * K;
  const u16* pb0 = B + (size_t)(bn0 + wave * 32 + srow) * K + scol;
  const u16* pb1 = pb0 + (size_t)16 * K;
  u16* la0 = lA + (wave * 32) * 32;
  u16* la1 = la0 + 16 * 32;
  u16* lb0 = lB + (wave * 32) * 32;
  u16* lb1 = lb0 + 16 * 32;

  const int fr = lane & 15, kq = lane >> 4;
  const u16* fA = lA + (wm * 64 + fr) * 32 + kq * 8;
  const u16* fB = lB + (wn * 64 + fr) * 32 + kq * 8;

  f4v acc[4][4];
  const f4v zf = {0.f, 0.f, 0.f, 0.f};
  for (int i = 0; i < 4; ++i)
    for (int j = 0; j < 4; ++j)
      acc[i][j] = zf;

  for (int k0 = 0; k0 < K; k0 += 32) {
    glds16(pa0 + k0, la0);
    glds16(pa1 + k0, la1);
    glds16(pb0 + k0, lb0);
    glds16(pb1 + k0, lb1);
    __syncthreads();
    s8v af[4], bfv[4];
#pragma unroll
    for (int i = 0; i < 4; ++i) af[i] = *(const s8v*)(fA + i * 16 * 32);
#pragma unroll
    for (int j = 0; j < 4; ++j) bfv[j] = *(const s8v*)(fB + j * 16 * 32);
#pragma unroll
    for (int i = 0; i < 4; ++i)
#pragma unroll
      for (int j = 0; j < 4; ++j)
        acc[i][j] = __builtin_amdgcn_mfma_f32_16x16x32_bf16(af[i], bfv[j], acc[i][j], 0, 0, 0);
    __syncthreads();
  }

  // C/D layout: col = lane&15, row = (lane>>4)*4 + reg
#pragma unroll
  for (int i = 0; i < 4; ++i) {
#pragma unroll
    for (int j = 0; j < 4; ++j) {
#pragma unroll
      for (int r = 0; r < 4; ++r) {
        const int gm = bm0 + wm * 64 + i * 16 + kq * 4 + r;
        const int gn = bn0 + wn * 64 + j * 16 + fr;
        const float val = acc[i][j][r];
        if (EPI == 0) {
          if (gn < D_INNER) {
            Cb[(size_t)gm * D_INNER + gn] = f2bf(val);
          } else {
            const float s = val / (1.f + __expf(-val));  // silu(z)
            Cb2[(size_t)gm * D_INNER + (gn - D_INNER)] = f2bf(s);
          }
        } else if (EPI == 4) {
          if (gn < D_INNER) {
            const float pre = val + bias[gn];
            const float sig = 1.f / (1.f + __expf(-pre));
            const float m = -expm1f(sfac[gn] * sig);   // 1 - lam, full precision
            Cb2[(size_t)gm * D_INNER + gn] = f2bf(m);
          } else {
            Cb[(size_t)gm * D_INNER + (gn - D_INNER)] = f2bf(val + bias2[gn - D_INNER]);
          }
        } else {
          Cf[(size_t)gm * N + gn] = val;
        }
      }
    }
  }
}

// ---------------------------------------------------------------------------
// Fused bf16 conversion of all 5 inputs in ONE launch (outputs contiguous
// in the carve: [x | Win | Wl | Wv | Wout], float4 units).
// ---------------------------------------------------------------------------
#define CV_R0 2097152   // x end        (8192*1024/4)
#define CV_R1 3145728   // Win end      (+4096*1024/4)
#define CV_R2 4194304   // Wl end       (+2048*2048/4)
#define CV_R3 5242880   // Wv end
#define CV_R4 5767168   // Wout end     (+1024*2048/4)  == grid*256 exactly

__global__ __launch_bounds__(256)
void convall_kernel(const float* __restrict__ x, const float* __restrict__ Win,
                    const float* __restrict__ Wl, const float* __restrict__ Wv,
                    const float* __restrict__ Wout, u16* __restrict__ outb)
{
  const int g = blockIdx.x * 256 + threadIdx.x;   // float4 index, < CV_R4
  const float* in; int lo;
  if (g < CV_R0)      { in = x;    lo = g; }
  else if (g < CV_R1) { in = Win;  lo = g - CV_R0; }
  else if (g < CV_R2) { in = Wl;   lo = g - CV_R1; }
  else if (g < CV_R3) { in = Wv;   lo = g - CV_R2; }
  else                { in = Wout; lo = g - CV_R3; }
  const float4 v = ((const float4*)in)[lo];
  U16x4 o; o.x = f2bf(v.x); o.y = f2bf(v.y); o.z = f2bf(v.z); o.w = f2bf(v.w);
  ((U16x4*)outb)[g] = o;
}

__global__ void sfac_kernel(const float* __restrict__ omega, float* __restrict__ sfac)
{
  const int i = blockIdx.x * blockDim.x + threadIdx.x;
  if (i < D_INNER) sfac[i] = -8.f * log1pf(expf(omega[i]));  // -C*softplus(omega)
}

// v <- v * sqrt(2/(v.v)) per row; 1 wave per row, 4 rows per block.
__global__ __launch_bounds__(256)
void vscale_kernel(u16* __restrict__ v)
{
  const int row  = blockIdx.x * 4 + (threadIdx.x >> 6);
  const int lane = threadIdx.x & 63;
  uint4* p = (uint4*)(v + (size_t)row * D_INNER + lane * 32);  // 32 ch/lane
  uint4 a[4];
#pragma unroll
  for (int i = 0; i < 4; ++i) a[i] = p[i];
  float s = 0.f;
#pragma unroll
  for (int i = 0; i < 4; ++i) {
    const unsigned w[4] = {a[i].x, a[i].y, a[i].z, a[i].w};
#pragma unroll
    for (int j = 0; j < 4; ++j) {
      const float f0 = blo(w[j]), f1 = bhi(w[j]);
      s += f0 * f0 + f1 * f1;
    }
  }
  s += __shfl_down(s, 32); s += __shfl_down(s, 16); s += __shfl_down(s, 8);
  s += __shfl_down(s, 4);  s += __shfl_down(s, 2);  s += __shfl_down(s, 1);
  const float sc = sqrtf(2.f / __shfl(s, 0));
#pragma unroll
  for (int i = 0; i < 4; ++i) {
    const unsigned w[4] = {a[i].x, a[i].y, a[i].z, a[i].w};
    unsigned o[4];
#pragma unroll
    for (int j = 0; j < 4; ++j) o[j] = pkbf(blo(w[j]) * sc, bhi(w[j]) * sc);
    uint4 ov; ov.x = o[0]; ov.y = o[1]; ov.z = o[2]; ov.w = o[3];
    p[i] = ov;
  }
}

// Pair precompute (round-4 verified), one wave per even t:
//   C1_t = (v_{t+1} - v_{t+1}*m_t) . v_t ;  C2_t = v_{t+1} . (m_t * x_t)
__global__ __launch_bounds__(256)
void pairprep_kernel(const u16* __restrict__ vs, const u16* __restrict__ mb,
                     const u16* __restrict__ xi, f32x2* __restrict__ C12)
{
  const int r = blockIdx.x * 4 + (threadIdx.x >> 6);  // r = b*1024 + t/2
  const int lane = threadIdx.x & 63;
  const int b = r >> 10;
  const int t = (r & 1023) * 2;
  const size_t o0 = ((size_t)b * TLEN + t) * D_INNER + (size_t)lane * 32;
  const size_t o1 = o0 + D_INNER;
  const uint4* pv0 = (const uint4*)(vs + o0);
  const uint4* pv1 = (const uint4*)(vs + o1);
  const uint4* px0 = (const uint4*)(xi + o0);
  const uint4* pm0 = (const uint4*)(mb + o0);
  float c1 = 0.f, c2 = 0.f;
#pragma unroll
  for (int i = 0; i < 4; ++i) {
    const uint4 v0 = pv0[i], v1 = pv1[i], x0 = px0[i], m0 = pm0[i];
    const unsigned v0w[4] = {v0.x, v0.y, v0.z, v0.w};
    const unsigned v1w[4] = {v1.x, v1.y, v1.z, v1.w};
    const unsigned x0w[4] = {x0.x, x0.y, x0.z, x0.w};
    const unsigned m0w[4] = {m0.x, m0.y, m0.z, m0.w};
#pragma unroll
    for (int q = 0; q < 4; ++q) {
      const float va = blo(v0w[q]), vb = bhi(v0w[q]);
      const float ua = blo(v1w[q]), ub = bhi(v1w[q]);
      const float xa = blo(x0w[q]), xb = bhi(x0w[q]);
      const float ma = blo(m0w[q]), mbv = bhi(m0w[q]);
      const float wa = __builtin_fmaf(-ua, ma, ua);    // v1*(1-m0), fp32
      const float wb = __builtin_fmaf(-ub, mbv, ub);
      c1 += wa * va + wb * vb;
      c2 += ua * (ma * xa) + ub * (mbv * xb);
    }
  }
  c1 = wave_sum_dpp(c1);
  c2 = wave_sum_dpp(c2);
  if (lane == 63) { f32x2 cc; cc.x = c1; cc.y = c2; C12[r] = cc; }
}

// gh <- sz * gh  elementwise (full chip), in-place over the h buffer
__global__ void zmul_kernel(u16* __restrict__ gh, const u16* __restrict__ sz, int n8)
{
  const int i = blockIdx.x * blockDim.x + threadIdx.x;
  if (i >= n8) return;
  const uint4 hv = ((const uint4*)gh)[i];
  const uint4 zv = ((const uint4*)sz)[i];
  const unsigned hw[4] = {hv.x, hv.y, hv.z, hv.w};
  const unsigned zw[4] = {zv.x, zv.y, zv.z, zv.w};
  unsigned ow[4];
#pragma unroll
  for (int q = 0; q < 4; ++q)
    ow[q] = pkbf(blo(zw[q]) * blo(hw[q]), bhi(zw[q]) * bhi(hw[q]));
  uint4 o; o.x = ow[0]; o.y = ow[1]; o.z = ow[2]; o.w = ow[3];
  ((uint4*)gh)[i] = o;
}

// ---------------------------------------------------------------------------
// Paired sequential scan — EXACT round-4 verified version (576 us, VGPR 76):
// 256 thr, 8 ch/thread, uint4 loads, separate-struct prefetch + sched_barrier,
// plain stores. Three structural variants (G=4, G=8, 512-thr) all regressed;
// this shape minimizes per-wave overhead (4 DPP chains, dwordx4 loads).
// ---------------------------------------------------------------------------
struct Pair {
  uint4 v0, v1, x0, x1, m0, m1;
  f32x2 c;
};

__global__ __launch_bounds__(256, 1)
void scan2_kernel(const u16* __restrict__ xi, const u16* __restrict__ vs,
                  const u16* __restrict__ mb, const f32x2* __restrict__ C12,
                  u16* __restrict__ hb)
{
  const int b = blockIdx.x, tid = threadIdx.x;
  const int wave = tid >> 6, lane = tid & 63;
  const size_t base = (size_t)b * TLEN * D_INNER + (size_t)tid * 8;
  const int cb0 = b * 1024;
  __shared__ __attribute__((aligned(16))) float rP[2][4], rQ[2][4];

  auto load_pair = [&](int t) {
    Pair p;
    const size_t o0 = base + (size_t)t * D_INNER;
    const size_t o1 = o0 + D_INNER;
    p.v0 = *(const uint4*)(vs + o0);
    p.v1 = *(const uint4*)(vs + o1);
    p.x0 = *(const uint4*)(xi + o0);
    p.x1 = *(const uint4*)(xi + o1);
    p.m0 = *(const uint4*)(mb + o0);
    p.m1 = *(const uint4*)(mb + o1);
    p.c = C12[cb0 + (t >> 1)];
    return p;
  };

  float h[8];
  {  // t = 0: h = xi (exact bf16 copy)
    const uint4 x0 = *(const uint4*)(xi + base);
    const unsigned xw[4] = {x0.x, x0.y, x0.z, x0.w};
#pragma unroll
    for (int p = 0; p < 4; ++p) {
      h[2*p]   = blo(xw[p]);
      h[2*p+1] = bhi(xw[p]);
    }
    *(uint4*)(hb + base) = x0;
  }

  {  // solo step t = 1
    const size_t o = base + D_INNER;
    const uint4 v1v = *(const uint4*)(vs + o);
    const uint4 x1v = *(const uint4*)(xi + o);
    const uint4 m1v = *(const uint4*)(mb + o);
    const unsigned vw[4] = {v1v.x, v1v.y, v1v.z, v1v.w};
    float vf[8];
    float P0 = 0.f, P1 = 0.f;
#pragma unroll
    for (int p = 0; p < 4; ++p) {
      vf[2*p]   = blo(vw[p]);
      vf[2*p+1] = bhi(vw[p]);
      P0 = __builtin_fmaf(vf[2*p],   h[2*p],   P0);
      P1 = __builtin_fmaf(vf[2*p+1], h[2*p+1], P1);
    }
    float P = wave_sum_dpp(P0 + P1);
    if (lane == 63) rP[0][wave] = P;
    asm volatile("s_waitcnt lgkmcnt(0)\n\ts_barrier" ::: "memory");
    const float4 sp = *(const float4*)rP[0];
    const float a = (sp.x + sp.y) + (sp.z + sp.w);
    const unsigned xw[4] = {x1v.x, x1v.y, x1v.z, x1v.w};
    const unsigned mw[4] = {m1v.x, m1v.y, m1v.z, m1v.w};
    unsigned ow[4];
#pragma unroll
    for (int p = 0; p < 4; ++p) {
      const float X0 = blo(xw[p]), X1 = bhi(xw[p]);
      const float M0 = blo(mw[p]), M1 = bhi(mw[p]);
      const float t0 = __builtin_fmaf(vf[2*p],   -a, h[2*p]);
      const float t1 = __builtin_fmaf(vf[2*p+1], -a, h[2*p+1]);
      h[2*p]   = __builtin_fmaf(M0, X0 - t0, t0);
      h[2*p+1] = __builtin_fmaf(M1, X1 - t1, t1);
      ow[p] = pkbf(h[2*p], h[2*p+1]);
    }
    uint4 out; out.x = ow[0]; out.y = ow[1]; out.z = ow[2]; out.w = ow[3];
    *(uint4*)(hb + o) = out;
  }

  auto round = [&](const Pair& p, int t) {
    const int par = (t >> 1) & 1;
    const unsigned v0w[4] = {p.v0.x, p.v0.y, p.v0.z, p.v0.w};
    const unsigned v1w[4] = {p.v1.x, p.v1.y, p.v1.z, p.v1.w};
    const unsigned m0w[4] = {p.m0.x, p.m0.y, p.m0.z, p.m0.w};
    float vf[8], uf[8], mf0[8];
    float P0 = 0.f, P1 = 0.f, Q0 = 0.f, Q1 = 0.f;
#pragma unroll
    for (int q = 0; q < 4; ++q) {
      vf[2*q]   = blo(v0w[q]);
      vf[2*q+1] = bhi(v0w[q]);
      uf[2*q]   = blo(v1w[q]);
      uf[2*q+1] = bhi(v1w[q]);
      mf0[2*q]  = blo(m0w[q]);
      mf0[2*q+1]= bhi(m0w[q]);
      const float wa = __builtin_fmaf(-uf[2*q],   mf0[2*q],   uf[2*q]);   // v1*l0
      const float wb = __builtin_fmaf(-uf[2*q+1], mf0[2*q+1], uf[2*q+1]);
      P0 = __builtin_fmaf(vf[2*q],   h[2*q],   P0);
      P1 = __builtin_fmaf(vf[2*q+1], h[2*q+1], P1);
      Q0 = __builtin_fmaf(wa, h[2*q],   Q0);
      Q1 = __builtin_fmaf(wb, h[2*q+1], Q1);
    }
    float P = wave_sum_dpp(P0 + P1);
    float Q = wave_sum_dpp(Q0 + Q1);
    if (lane == 63) { rP[par][wave] = P; rQ[par][wave] = Q; }
    asm volatile("s_waitcnt lgkmcnt(0)\n\ts_barrier" ::: "memory");
    const float4 sp = *(const float4*)rP[par];
    const float4 sq = *(const float4*)rQ[par];
    const float a0 = (sp.x + sp.y) + (sp.z + sp.w);
    const float a1 = __builtin_fmaf(-a0, p.c.x, (sq.x + sq.y) + (sq.z + sq.w) + p.c.y);
    const unsigned xw0[4] = {p.x0.x, p.x0.y, p.x0.z, p.x0.w};
    const unsigned xw1[4] = {p.x1.x, p.x1.y, p.x1.z, p.x1.w};
    const unsigned m1w[4] = {p.m1.x, p.m1.y, p.m1.z, p.m1.w};
    unsigned ow0[4], ow1[4];
#pragma unroll
    for (int q = 0; q < 4; ++q) {
      const float A0 = blo(xw0[q]), A1 = bhi(xw0[q]);
      const float B0 = blo(xw1[q]), B1 = bhi(xw1[q]);
      const float N0 = blo(m1w[q]), N1 = bhi(m1w[q]);
      float t0 = __builtin_fmaf(vf[2*q],   -a0, h[2*q]);
      float t1 = __builtin_fmaf(vf[2*q+1], -a0, h[2*q+1]);
      t0 = __builtin_fmaf(mf0[2*q],   A0 - t0, t0);   // h_t
      t1 = __builtin_fmaf(mf0[2*q+1], A1 - t1, t1);
      ow0[q] = pkbf(t0, t1);
      const float u0 = __builtin_fmaf(uf[2*q],   -a1, t0);
      const float u1 = __builtin_fmaf(uf[2*q+1], -a1, t1);
      h[2*q]   = __builtin_fmaf(N0, B0 - u0, u0);     // h_{t+1}
      h[2*q+1] = __builtin_fmaf(N1, B1 - u1, u1);
      ow1[q] = pkbf(h[2*q], h[2*q+1]);
    }
    const size_t oo = base + (size_t)t * D_INNER;
    uint4 o0; o0.x = ow0[0]; o0.y = ow0[1]; o0.z = ow0[2]; o0.w = ow0[3];
    uint4 o1; o1.x = ow1[0]; o1.y = ow1[1]; o1.z = ow1[2]; o1.w = ow1[3];
    *(uint4*)(hb + oo) = o0;
    *(uint4*)(hb + oo + D_INNER) = o1;
  };

  // Software pipeline, depth = 2 rounds; sched_barrier(0) pins load clumps.
  Pair A = load_pair(2);
  __builtin_amdgcn_sched_barrier(0);
  Pair B = load_pair(4);
  __builtin_amdgcn_sched_barrier(0);
  for (int t = 2; t <= 2038; t += 4) {
    Pair An = load_pair(t + 4);
    __builtin_amdgcn_sched_barrier(0);
    round(A, t);
    A = An;
    Pair Bn = load_pair(t + 6);
    __builtin_amdgcn_sched_barrier(0);
    round(B, t + 2);
    B = Bn;
  }
  {
    Pair An = load_pair(2046);
    __builtin_amdgcn_sched_barrier(0);
    round(A, 2042);
    round(B, 2044);
    round(An, 2046);
  }
}

extern "C" void kernel_launch(void* const* d_in, const int* in_sizes, int n_in,
                              void* d_out, int out_size, void* d_ws, size_t ws_size,
                              hipStream_t stream)
{
  const float* x     = (const float*)d_in[0];
  const float* omega = (const float*)d_in[1];
  const float* Win   = (const float*)d_in[2];
  const float* Wl    = (const float*)d_in[3];
  const float* bl    = (const float*)d_in[4];
  const float* Wv    = (const float*)d_in[5];
  const float* bv    = (const float*)d_in[6];
  const float* Wout  = (const float*)d_in[7];
  float* out = (float*)d_out;
  (void)in_sizes; (void)n_in; (void)out_size; (void)ws_size;

  size_t off = 0;
  auto carve = [&](size_t bytes) -> void* {
    void* r = (char*)d_ws + off;
    off += (bytes + 255) & ~(size_t)255;
    return r;
  };
  u16*  x_bf    = (u16*)carve((size_t)BT * D_MODEL * 2);          // conv region base
  u16*  Win_bf  = (u16*)carve((size_t)2 * D_INNER * D_MODEL * 2);
  u16*  Wl_bf   = (u16*)carve((size_t)D_INNER * D_INNER * 2);
  u16*  Wv_bf   = (u16*)carve((size_t)D_INNER * D_INNER * 2);
  u16*  Wout_bf = (u16*)carve((size_t)D_MODEL * D_INNER * 2);
  u16*  xi_bf   = (u16*)carve((size_t)BT * D_INNER * 2);
  u16*  sz_bf   = (u16*)carve((size_t)BT * D_INNER * 2);
  u16*  v_bf    = (u16*)carve((size_t)BT * D_INNER * 2);
  u16*  gh_bf   = (u16*)carve((size_t)BT * D_INNER * 2);   // scan h, then z*h in-place
  u16*  mb      = (u16*)carve((size_t)BT * D_INNER * 2);   // 1-lam, bf16
  float* sfac   = (float*)carve((size_t)D_INNER * 4);
  f32x2* C12    = (f32x2*)carve((size_t)(BT / 2) * 8);

  // all 5 input conversions in one launch (outputs contiguous from x_bf)
  convall_kernel<<<CV_R4 / 256, 256, 0, stream>>>(x, Win, Wl, Wv, Wout, x_bf);
  sfac_kernel<<<(D_INNER + 255) / 256, 256, 0, stream>>>(omega, sfac);

  // xz = x @ Win^T  -> xi (bf16) | silu(z) (bf16)
  gemm_nt<0><<<dim3(4096 / 128, BT / 128), 256, 0, stream>>>(
      x_bf, Win_bf, BT, 4096, D_MODEL, nullptr, xi_bf, sz_bf, nullptr, nullptr, nullptr);
  // merged: mb = bf16(1-lam) | v = xi@Wv^T+bv bf16
  gemm_nt<4><<<dim3(4096 / 128, BT / 128), 256, 0, stream>>>(
      xi_bf, Wl_bf, BT, 4096, D_INNER, nullptr, v_bf, mb, bl, sfac, bv);
  // v <- v*sqrt(2/(v.v))
  vscale_kernel<<<BT / 4, 256, 0, stream>>>(v_bf);
  // pair cross-terms: C12 = (C1,C2)
  pairprep_kernel<<<BT / 2 / 4, 256, 0, stream>>>(v_bf, mb, xi_bf, C12);
  // paired sequential scan (round-4 exact) -> hb = h (bf16)
  scan2_kernel<<<NBATCH, 256, 0, stream>>>(xi_bf, v_bf, mb, C12, gh_bf);
  // gh = silu(z)*h (full chip, in-place)
  zmul_kernel<<<(BT * D_INNER / 8 + 255) / 256, 256, 0, stream>>>(gh_bf, sz_bf, BT * D_INNER / 8);
  // out = gh @ Wout^T (fp32)
  gemm_nt<3><<<dim3(D_MODEL / 128, BT / 128), 256, 0, stream>>>(
      gh_bf, Wout_bf, BT, D_MODEL, D_INNER, out, nullptr, nullptr, nullptr, nullptr, nullptr);
}